// Round 2
// baseline (2627.879 us; speedup 1.0000x reference)
//
#include <hip/hip_runtime.h>
#include <math.h>

#define LSEQ 2048
#define NB 8
#define NCH 64
#define NTOT (NB*NCH*LSEQ)   // 1048576
#define NROWS (NB*NCH)       // 512

__device__ __forceinline__ float geluf(float x){
    return 0.5f*x*(1.0f+erff(x*0.70710678118654752f));
}
__device__ __forceinline__ float siluf(float x){
    return x/(1.0f+expf(-x));
}
__device__ __forceinline__ float sigf(float x){
    return 1.0f/(1.0f+expf(-x));
}

// ---------------- weight transpose: w[64][64][3] -> wt[192][64] --------------
__global__ __launch_bounds__(256) void wtrans_kernel(const float* __restrict__ w,
                                                     float* __restrict__ wt){
    int idx = blockIdx.x*256 + threadIdx.x;   // 12288 total
    int j = idx >> 6, co = idx & 63;
    wt[idx] = w[co*192 + j];
}

// ---------------- stat = mean over L ----------------------------------------
__global__ __launch_bounds__(256) void stat_kernel(const float* __restrict__ in,
                                                   float* __restrict__ stat){
    int r = blockIdx.x, tid = threadIdx.x;
    const float* p = in + (size_t)r*LSEQ;
    float acc = 0.f;
    for (int i=tid;i<LSEQ;i+=256) acc += p[i];
    for (int o=32;o>0;o>>=1) acc += __shfl_down(acc,o,64);
    __shared__ float red[4];
    if ((tid&63)==0) red[tid>>6]=acc;
    __syncthreads();
    if (tid==0) stat[r] = (red[0]+red[1]+red[2]+red[3])*(1.0f/LSEQ);
}

// ---------------- dywan MLP + filters + ortho -------------------------------
__global__ __launch_bounds__(256) void dywan_kernel(
    const float* __restrict__ stat,
    const float* __restrict__ w1, const float* __restrict__ b1,
    const float* __restrict__ wg1, const float* __restrict__ bg1,
    const float* __restrict__ wg2, const float* __restrict__ bg2,
    float* __restrict__ lo_out, float* __restrict__ hi_out,
    float* __restrict__ ortho_out)
{
    __shared__ float st[512];
    __shared__ float h1s[512];
    __shared__ float h2s[1024];
    __shared__ float fs[112];
    int tid = threadIdx.x;
    for (int i=tid;i<512;i+=256) st[i]=stat[i];
    __syncthreads();
    for (int idx=tid; idx<512; idx+=256){
        int b=idx>>6, j=idx&63;
        float acc=b1[j];
        const float* W=w1+j*64;
        for (int i=0;i<64;i++) acc += st[b*64+i]*W[i];
        h1s[idx]=geluf(acc);
    }
    __syncthreads();
    for (int idx=tid; idx<1024; idx+=256){
        int b=idx>>7, j=idx&127;
        float acc=bg1[j];
        const float* W=wg1+j*64;
        for (int i=0;i<64;i++) acc += h1s[b*64+i]*W[i];
        h2s[idx]=geluf(acc);
    }
    __syncthreads();
    if (tid<112){
        int b=tid/14, j=tid-b*14;
        float acc=bg2[j];
        const float* W=wg2+j*128;
        for (int i=0;i<128;i++) acc += h2s[b*128+i]*W[i];
        fs[tid]=acc;
    }
    __syncthreads();
    if (tid<56){
        int b=tid/7, k=tid-b*7;
        lo_out[tid]=fs[b*14+k];
        hi_out[tid]=fs[b*14+7+k];
    }
    if (tid==0){
        float smooth=0.f, shiftsum=0.f, ampsum=0.f;
        for (int b=0;b<8;b++){
            const float* l = fs + b*14;   // lo row
            float prev=0.f, nrm=0.f;
            for (int k=0;k<7;k++){ smooth += fabsf(l[k]-prev); prev=l[k]; nrm += l[k]*l[k]; }
            smooth += fabsf(prev);
            float denom = sqrtf(nrm) + 1e-8f;
            float sabs=0.f, s2=0.f;
            for (int k=0;k<7;k++){ float v=l[k]/denom; sabs+=fabsf(v); s2+=v*v; }
            shiftsum += sabs*sabs;
            ampsum += fabsf(s2-1.0f);
        }
        smooth *= (1.0f/64.0f);
        float shift = 3.0f*shiftsum/(8.0f*49.0f);
        float amp = ampsum*(1.0f/8.0f);
        *ortho_out = 0.01f*(shift+amp) + 0.1f*smooth;
    }
}

// ---------------- per-batch 7-tap filter conv (edge pad) --------------------
__global__ __launch_bounds__(256) void filt_kernel(
    const float* __restrict__ ap, const float* __restrict__ lo,
    const float* __restrict__ hi, float* __restrict__ na,
    float* __restrict__ det)
{
    int r = blockIdx.y, l0 = blockIdx.x*256, tid = threadIdx.x;
    int b = r>>6;
    __shared__ float s[262];
    __shared__ float fl[7], fh[7];
    for (int idx=tid; idx<262; idx+=256){
        int l = l0+idx-3;
        l = min(max(l,0),LSEQ-1);
        s[idx]=ap[(size_t)r*LSEQ+l];
    }
    if (tid<7) fl[tid]=lo[b*7+tid];
    else if (tid<14) fh[tid-7]=hi[b*7+tid-7];
    __syncthreads();
    float a=0.f, d=0.f;
    #pragma unroll
    for (int k=0;k<7;k++){ float v=s[tid+k]; a+=v*fl[k]; d+=v*fh[k]; }
    na[(size_t)r*LSEQ+l0+tid]=a;
    det[(size_t)r*LSEQ+l0+tid]=d;
}

// ---------------- time grid pass1: per-row stats ----------------------------
__global__ __launch_bounds__(256) void tg_pass1(const float* __restrict__ C,
                                                float* __restrict__ rowstats){
    __shared__ float sh[2048];
    __shared__ float red[28];
    int r = blockIdx.x, tid = threadIdx.x;
    const float* s = C + (size_t)r*LSEQ;
    for (int i=tid;i<2048;i+=256) sh[i]=s[i];
    __syncthreads();
    float ssq=0.f;
    for (int i=tid;i<2048;i+=256){ float v=sh[i]; ssq+=v*v; }
    float mn=1e30f, mx=-1e30f, s0=0.f,s1=0.f,s2=0.f,s3=0.f;
    for (int j=tid;j<2047;j+=256){
        int k0 = (j-2>0)? j-2:0;
        int k1 = (j+2<2046)? j+2:2046;
        float acc=0.f;
        for (int k=k0;k<=k1;k++) acc += fabsf(sh[k+1]-sh[k]);
        float inten = acc*0.2f;
        mn=fminf(mn,inten); mx=fmaxf(mx,inten);
        if (j<511)  s0+=inten;
        if (j<1023) s1+=inten;
        if (j<1534) s2+=inten;
        if (j<2046) s3+=inten;
    }
    float vals[7]={mn,mx,s0,s1,s2,s3,ssq};
    for (int o=32;o>0;o>>=1){
        vals[0]=fminf(vals[0],__shfl_down(vals[0],o,64));
        vals[1]=fmaxf(vals[1],__shfl_down(vals[1],o,64));
        vals[2]+=__shfl_down(vals[2],o,64);
        vals[3]+=__shfl_down(vals[3],o,64);
        vals[4]+=__shfl_down(vals[4],o,64);
        vals[5]+=__shfl_down(vals[5],o,64);
        vals[6]+=__shfl_down(vals[6],o,64);
    }
    int lane=tid&63, w=tid>>6;
    if (lane==0) for (int q=0;q<7;q++) red[w*7+q]=vals[q];
    __syncthreads();
    if (tid==0){
        rowstats[r*8+0]=fminf(fminf(red[0],red[7]),fminf(red[14],red[21]));
        rowstats[r*8+1]=fmaxf(fmaxf(red[1],red[8]),fmaxf(red[15],red[22]));
        rowstats[r*8+2]=red[2]+red[9]+red[16]+red[23];
        rowstats[r*8+3]=red[3]+red[10]+red[17]+red[24];
        rowstats[r*8+4]=red[4]+red[11]+red[18]+red[25];
        rowstats[r*8+5]=red[5]+red[12]+red[19]+red[26];
        rowstats[r*8+6]=red[6]+red[13]+red[20]+red[27];
    }
}

// ---------------- time grid finalize + modulation vectors -------------------
__global__ __launch_bounds__(256) void tg_finalize(
    const float* __restrict__ rs,
    const float* __restrict__ wt, const float* __restrict__ bt,
    const float* __restrict__ wm, const float* __restrict__ bm,
    const float* __restrict__ emb, int lvl,
    float* __restrict__ ts_out, float* __restrict__ modsc,
    float* __restrict__ modbi, float* __restrict__ ein,
    float* __restrict__ eout)
{
    int tid=threadIdx.x;
    __shared__ float red[28];
    __shared__ float stv[9];
    __shared__ float temb[144];
    float mn=1e30f,mx=-1e30f,a0=0.f,a1=0.f,a2=0.f,a3=0.f,m3=-1e30f;
    for (int r=tid;r<512;r+=256){
        mn=fminf(mn,rs[r*8+0]); mx=fmaxf(mx,rs[r*8+1]);
        a0+=rs[r*8+2]; a1+=rs[r*8+3]; a2+=rs[r*8+4]; a3+=rs[r*8+5];
        m3=fmaxf(m3,rs[r*8+5]);
    }
    float vals[7]={mn,mx,a0,a1,a2,a3,m3};
    for (int o=32;o>0;o>>=1){
        vals[0]=fminf(vals[0],__shfl_down(vals[0],o,64));
        vals[1]=fmaxf(vals[1],__shfl_down(vals[1],o,64));
        vals[2]+=__shfl_down(vals[2],o,64);
        vals[3]+=__shfl_down(vals[3],o,64);
        vals[4]+=__shfl_down(vals[4],o,64);
        vals[5]+=__shfl_down(vals[5],o,64);
        vals[6]=fmaxf(vals[6],__shfl_down(vals[6],o,64));
    }
    int lane=tid&63, w=tid>>6;
    if (lane==0) for (int q=0;q<7;q++) red[w*7+q]=vals[q];
    // per-batch energy of input + zero e_out
    if (tid<8){
        float e=0.f;
        for (int c=0;c<64;c++) e += rs[(tid*64+c)*8+6];
        ein[tid]=e*(1.0f/131072.0f);
        eout[tid]=0.f;
    }
    __syncthreads();
    if (tid==0){
        float mnv=fminf(fminf(red[0],red[7]),fminf(red[14],red[21]));
        float mxv=fmaxf(fmaxf(red[1],red[8]),fmaxf(red[15],red[22]));
        float s0=red[2]+red[9]+red[16]+red[23];
        float s1=red[3]+red[10]+red[17]+red[24];
        float s2=red[4]+red[11]+red[18]+red[25];
        float s3=red[5]+red[12]+red[19]+red[26];
        float m3v=fmaxf(fmaxf(red[6],red[13]),fmaxf(red[20],red[27]));
        const float idxs[5]={0.f,511.f,1023.f,1534.f,2046.f};
        float tsv[5];
        if (mxv-mnv < 1e-8f){
            for (int k=0;k<5;k++) tsv[k]=idxs[k]/2046.0f;
        } else {
            float a = 0.9f/(mxv-mnv+1e-30f);
            float bb = 0.1f - a*mnv;
            float gmax = a*m3v + bb*2046.0f;
            float sums[5]={0.f,s0,s1,s2,s3};
            tsv[0]=0.f;
            for (int k=1;k<5;k++)
                tsv[k]=(a*(sums[k]*(1.0f/512.0f)) + bb*idxs[k])/gmax;
        }
        for (int k=0;k<5;k++){ ts_out[k]=tsv[k]; stv[2*k]=tsv[k]; }
        for (int k=0;k<4;k++) stv[2*k+1]=tsv[k] + 0.5f*(tsv[k+1]-tsv[k]);
    }
    __syncthreads();
    if (tid<144){
        int m=tid>>4, i=tid&15;
        float z = wt[lvl*16+i]*stv[m] + bt[lvl*16+i];
        temb[tid]=siluf(z);
    }
    __syncthreads();
    for (int idx=tid; idx<1152; idx+=256){
        int m=idx>>7, c=idx&127;
        float g=bm[lvl*128+c];
        const float* W=wm+(size_t)(lvl*128+c)*16;
        const float* te=temb+m*16;
        for (int i=0;i<16;i++) g += W[i]*te[i];
        if (c<64) modsc[m*64+c]=1.0f+g+emb[(lvl*8+lvl)*64+c];
        else      modbi[m*64+(c-64)]=g;
    }
}

// ---------------- fused ode_f eval (conv-gelu-conv-mod-silu) ----------------
__global__ __launch_bounds__(256) void ode_eval_kernel(
    const float* __restrict__ yin, const float* __restrict__ kprev,
    const float* __restrict__ w1t, const float* __restrict__ b1,
    const float* __restrict__ w2t, const float* __restrict__ b2,
    const float* __restrict__ modsc, const float* __restrict__ modbi,
    const float* __restrict__ ts, int step, int eval,
    float* __restrict__ kout, float* __restrict__ acc,
    float* __restrict__ yout, float* __restrict__ eout, int do_energy)
{
    __shared__ float ye[64][72];
    __shared__ float hs[64][66];
    __shared__ float red[4];
    const int tid=threadIdx.x;
    const int b=blockIdx.y;
    const int l0=blockIdx.x*64;
    const float dt = ts[step+1]-ts[step];
    const float alpha = (eval==0)?0.0f:((eval==3)?dt:0.5f*dt);
    const int tslot = 2*step + ((eval==0)?0:((eval==3)?2:1));
    // stage 0: y_eval = yin + alpha*kprev with halo 2, zero pad at seq ends
    for (int idx=tid; idx<64*68; idx+=256){
        int ci=idx/68, u=idx-ci*68;
        int l=l0+u-2;
        float v=0.f;
        if (l>=0 && l<LSEQ){
            size_t gi=(size_t)(b*64+ci)*LSEQ+l;
            v=yin[gi];
            if (eval!=0) v += alpha*kprev[gi];
        }
        ye[ci][u]=v;
    }
    __syncthreads();
    const int co=tid&63, g=tid>>6;
    // stage 1: conv1 + gelu -> hs[co][v], v in [0,66)
    // NOTE: h positions outside [0,LSEQ) must be ZERO (conv2's zero padding
    // in the reference pads h itself, not conv1 of padded input).
    {
        const int v0=g*17;
        const int nv=(g==3)?15:17;
        float a[17];
        float bb=b1[co];
        #pragma unroll
        for (int i=0;i<17;i++) a[i]=bb;
        for (int ci=0;ci<64;ci++){
            float w0=w1t[(ci*3+0)*64+co];
            float w1_=w1t[(ci*3+1)*64+co];
            float w2_=w1t[(ci*3+2)*64+co];
            float x[19];
            #pragma unroll
            for (int j=0;j<19;j++) x[j]=ye[ci][v0+j];
            #pragma unroll
            for (int i=0;i<17;i++) a[i] += w0*x[i]+w1_*x[i+1]+w2_*x[i+2];
        }
        for (int i=0;i<nv;i++){
            int ph = l0 + v0 + i - 1;           // global h position
            float hv = geluf(a[i]);
            hs[co][v0+i] = (ph>=0 && ph<LSEQ) ? hv : 0.f;
        }
    }
    __syncthreads();
    // stage 2: conv2 + modulation + silu -> kv
    float kv[16];
    {
        const int p0=g*16;
        float c[16];
        float bb=b2[co];
        #pragma unroll
        for (int i=0;i<16;i++) c[i]=bb;
        for (int ci=0;ci<64;ci++){
            float w0=w2t[(ci*3+0)*64+co];
            float w1_=w2t[(ci*3+1)*64+co];
            float w2_=w2t[(ci*3+2)*64+co];
            float x[18];
            #pragma unroll
            for (int j=0;j<18;j++) x[j]=hs[ci][p0+j];
            #pragma unroll
            for (int i=0;i<16;i++) c[i] += w0*x[i]+w1_*x[i+1]+w2_*x[i+2];
        }
        float sc=modsc[tslot*64+co];
        float bi=modbi[tslot*64+co];
        #pragma unroll
        for (int i=0;i<16;i++){
            float m=c[i]*sc+bi;
            kv[i]=siluf(m)-0.1f*ye[co][p0+i+2];
        }
    }
    __syncthreads();
    {
        const int p0=g*16;
        #pragma unroll
        for (int i=0;i<16;i++) hs[co][p0+i]=kv[i];
    }
    __syncthreads();
    // epilogue: coalesced global updates
    float esum=0.f;
    const float dt6=dt/6.0f;
    for (int idx=tid; idx<4096; idx+=256){
        int ci=idx>>6, p=idx&63;
        float k=hs[ci][p];
        size_t gi=(size_t)(b*64+ci)*LSEQ + l0+p;
        if (eval==0){ kout[gi]=k; acc[gi]=k; }
        else if (eval<3){ kout[gi]=k; acc[gi]+=2.0f*k; }
        else {
            float yn=yin[gi]+dt6*(acc[gi]+k);
            yout[gi]=yn;
            esum+=yn*yn;
        }
    }
    if (do_energy){
        for (int o=32;o>0;o>>=1) esum+=__shfl_down(esum,o,64);
        if ((tid&63)==0) red[tid>>6]=esum;
        __syncthreads();
        if (tid==0) atomicAdd(&eout[b], red[0]+red[1]+red[2]+red[3]);
    }
}

// ---------------- energy renorm ---------------------------------------------
__global__ __launch_bounds__(256) void scale_kernel(
    const float* __restrict__ y, const float* __restrict__ ein,
    const float* __restrict__ eout, float* __restrict__ o)
{
    int idx = blockIdx.x*256 + threadIdx.x;
    int b = idx>>17;   // 64*2048 = 131072 per batch
    float eo = eout[b]*(1.0f/131072.0f);
    o[idx] = y[idx]*sqrtf(ein[b]/(eo+1e-8f));
}

// ---------------- 1x1 attention, detail *= (1+a) in place -------------------
__global__ __launch_bounds__(256) void attn_kernel(
    const float* __restrict__ cur, float* __restrict__ detail,
    const float* __restrict__ a1w, const float* __restrict__ a1b,
    const float* __restrict__ a2w, const float* __restrict__ a2b)
{
    __shared__ float c[64][64];
    __shared__ float hid[16][64];
    const int tid=threadIdx.x, b=blockIdx.y, l0=blockIdx.x*64;
    for (int idx=tid; idx<4096; idx+=256){
        int ci=idx>>6, p=idx&63;
        c[ci][p]=cur[(size_t)(b*64+ci)*LSEQ+l0+p];
    }
    __syncthreads();
    for (int idx=tid; idx<1024; idx+=256){
        int h=idx>>6, p=idx&63;
        float acc=a1b[h];
        const float* W=a1w+h*64;
        for (int ci=0;ci<64;ci++) acc += W[ci]*c[ci][p];
        hid[h][p]=geluf(acc);
    }
    __syncthreads();
    for (int idx=tid; idx<4096; idx+=256){
        int co=idx>>6, p=idx&63;
        float acc=a2b[co];
        const float* W=a2w+co*16;
        #pragma unroll
        for (int h=0;h<16;h++) acc += W[h]*hid[h][p];
        float a=sigf(acc);
        size_t gi=(size_t)(b*64+co)*LSEQ+l0+p;
        detail[gi] *= (1.0f+a);
    }
}

// ---------------- gate conv + residual update -------------------------------
__global__ __launch_bounds__(256) void gate_kernel(
    const float* __restrict__ cur, const float* __restrict__ detail,
    const float* __restrict__ gwt, const float* __restrict__ gb,
    float* __restrict__ curout)
{
    __shared__ float yc[64][66];
    __shared__ float dtile[64][65];
    const int tid=threadIdx.x, b=blockIdx.y, l0=blockIdx.x*64;
    for (int idx=tid; idx<64*66; idx+=256){
        int ci=idx/66, u=idx-ci*66;
        int l=l0+u-1;
        yc[ci][u]=(l>=0 && l<LSEQ)? cur[(size_t)(b*64+ci)*LSEQ+l] : 0.f;
    }
    for (int idx=tid; idx<4096; idx+=256){
        int ci=idx>>6, p=idx&63;
        dtile[ci][p]=detail[(size_t)(b*64+ci)*LSEQ+l0+p];
    }
    __syncthreads();
    const int co=tid&63, g=tid>>6;
    const int p0=g*16;
    float a[16];
    float bb=gb[co];
    #pragma unroll
    for (int i=0;i<16;i++) a[i]=bb;
    for (int ci=0;ci<64;ci++){
        float w0=gwt[(ci*3+0)*64+co];
        float w1_=gwt[(ci*3+1)*64+co];
        float w2_=gwt[(ci*3+2)*64+co];
        float x[18];
        #pragma unroll
        for (int j=0;j<18;j++) x[j]=yc[ci][p0+j];
        #pragma unroll
        for (int i=0;i<16;i++) a[i] += w0*x[i]+w1_*x[i+1]+w2_*x[i+2];
    }
    float r[16];
    #pragma unroll
    for (int i=0;i<16;i++){
        float gt=sigf(a[i]);
        r[i]=yc[co][p0+i+1]+gt*dtile[co][p0+i];
    }
    __syncthreads();
    #pragma unroll
    for (int i=0;i<16;i++) dtile[co][p0+i]=r[i];
    __syncthreads();
    for (int idx=tid; idx<4096; idx+=256){
        int ci=idx>>6, p=idx&63;
        curout[(size_t)(b*64+ci)*LSEQ+l0+p]=dtile[ci][p];
    }
}

extern "C" void kernel_launch(void* const* d_in, const int* in_sizes, int n_in,
                              void* d_out, int out_size, void* d_ws, size_t ws_size,
                              hipStream_t stream)
{
    (void)in_sizes; (void)n_in; (void)out_size; (void)ws_size;
    const float* x       =(const float*)d_in[0];
    const float* dy_w1   =(const float*)d_in[1];
    const float* dy_b1   =(const float*)d_in[2];
    const float* dy_wg1  =(const float*)d_in[3];
    const float* dy_bg1  =(const float*)d_in[4];
    const float* dy_wg2  =(const float*)d_in[5];
    const float* dy_bg2  =(const float*)d_in[6];
    const float* ode_c1w =(const float*)d_in[7];
    const float* ode_c1b =(const float*)d_in[8];
    const float* ode_c2w =(const float*)d_in[9];
    const float* ode_c2b =(const float*)d_in[10];
    const float* ode_wt  =(const float*)d_in[11];
    const float* ode_bt  =(const float*)d_in[12];
    const float* ode_wm  =(const float*)d_in[13];
    const float* ode_bm  =(const float*)d_in[14];
    const float* ode_emb =(const float*)d_in[15];
    const float* gate_w  =(const float*)d_in[16];
    const float* gate_b  =(const float*)d_in[17];
    const float* attn1_w =(const float*)d_in[18];
    const float* attn1_b =(const float*)d_in[19];
    const float* attn2_w =(const float*)d_in[20];
    const float* attn2_b =(const float*)d_in[21];
    float* out=(float*)d_out;
    float* ws=(float*)d_ws;
    const size_t N=NTOT;
    // workspace layout (floats): needs ~36.6 MB
    float* A0 =ws;
    float* Y0 =ws+N;       // also decomposition ping buffer
    float* D1 =ws+2*N;
    float* D2 =ws+3*N;
    float* D3 =ws+4*N;
    float* Y1 =ws+5*N;
    float* K0 =ws+6*N;
    float* K1 =ws+7*N;
    float* ACC=ws+8*N;
    float* SM =ws+9*N;
    float* stat_ws =SM;
    float* lo_ws   =SM+512;
    float* hi_ws   =SM+576;
    float* rowstats=SM+1024;   // 512*8
    float* ts_ws   =SM+5200;   // 5
    float* modsc   =SM+5248;   // 9*64
    float* modbi   =SM+5824;   // 9*64
    float* ein     =SM+6400;   // 8
    float* eoutb   =SM+6408;   // 8
    float* WT      =SM+8192;   // 8 * 12288 (ode conv weights, transposed)
    float* WTG     =WT+8*12288;// 3 * 12288 (gate weights, transposed)

    dim3 blk(256);

    // one-time weight transposes (per call; cheap)
    for (int lvl=0;lvl<4;lvl++){
        wtrans_kernel<<<48,blk,0,stream>>>(ode_c1w+(size_t)lvl*12288, WT+(size_t)(2*lvl)*12288);
        wtrans_kernel<<<48,blk,0,stream>>>(ode_c2w+(size_t)lvl*12288, WT+(size_t)(2*lvl+1)*12288);
    }
    for (int i=0;i<3;i++)
        wtrans_kernel<<<48,blk,0,stream>>>(gate_w+(size_t)i*12288, WTG+(size_t)i*12288);

    // ---- wavelet decomposition (3 levels) ----
    const float* cura=x;
    float* outsA[3]={A0, Y0, A0};
    float* outsD[3]={D1, D2, D3};
    for (int lv=0; lv<3; lv++){
        stat_kernel<<<NROWS,blk,0,stream>>>(cura, stat_ws);
        dywan_kernel<<<1,blk,0,stream>>>(stat_ws, dy_w1,dy_b1,dy_wg1,dy_bg1,dy_wg2,dy_bg2,
                                         lo_ws, hi_ws, out+4*N);
        filt_kernel<<<dim3(8,NROWS),blk,0,stream>>>(cura, lo_ws, hi_ws, outsA[lv], outsD[lv]);
        cura=outsA[lv];
    }
    const float* coeff[4]={A0,D1,D2,D3};

    // ---- per-level adaptive grid + RK4 + energy renorm ----
    for (int lvl=0;lvl<4;lvl++){
        tg_pass1<<<NROWS,blk,0,stream>>>(coeff[lvl], rowstats);
        tg_finalize<<<1,blk,0,stream>>>(rowstats, ode_wt, ode_bt, ode_wm, ode_bm,
                                        ode_emb, lvl, ts_ws, modsc, modbi, ein, eoutb);
        const float* w1t=WT+(size_t)(2*lvl)*12288;
        const float* w2t=WT+(size_t)(2*lvl+1)*12288;
        const float* b1=ode_c1b+lvl*64;
        const float* b2=ode_c2b+lvl*64;
        float* youts[4]={Y0,Y1,Y0,Y1};
        for (int step=0;step<4;step++){
            const float* yin=(step==0)?coeff[lvl]:youts[step-1];
            for (int ev=0;ev<4;ev++){
                const float* kp=(ev==0)?nullptr:((ev==1)?K0:((ev==2)?K1:K0));
                float* ko=(ev==0)?K0:((ev==1)?K1:((ev==2)?K0:nullptr));
                float* yo=(ev==3)?youts[step]:nullptr;
                int doe=(step==3 && ev==3)?1:0;
                ode_eval_kernel<<<dim3(32,NB),blk,0,stream>>>(
                    yin,kp,w1t,b1,w2t,b2,modsc,modbi,ts_ws,step,ev,ko,ACC,yo,eoutb,doe);
            }
        }
        scale_kernel<<<NTOT/256,blk,0,stream>>>(Y1, ein, eoutb, out+(size_t)lvl*N);
    }

    // ---- reconstruction ----
    // i=2: detail = evolved[3] (out slot 3, unchanged); current: out0 -> Y0
    gate_kernel<<<dim3(32,NB),blk,0,stream>>>(out+0*N, out+3*N, WTG+2*12288, gate_b+2*64, Y0);
    // i=1: attn modifies out slot 2 in place, then gate: Y0 -> Y1
    attn_kernel<<<dim3(32,NB),blk,0,stream>>>(Y0, out+2*N, attn1_w+1024, attn1_b+16,
                                              attn2_w+1024, attn2_b+64);
    gate_kernel<<<dim3(32,NB),blk,0,stream>>>(Y0, out+2*N, WTG+1*12288, gate_b+64, Y1);
    // i=0: attn modifies out slot 1 in place, then gate: Y1 -> out slot 0
    attn_kernel<<<dim3(32,NB),blk,0,stream>>>(Y1, out+1*N, attn1_w, attn1_b,
                                              attn2_w, attn2_b);
    gate_kernel<<<dim3(32,NB),blk,0,stream>>>(Y1, out+1*N, WTG, gate_b, out+0*N);
}

// Round 3
// 2505.398 us; speedup vs baseline: 1.0489x; 1.0489x over previous
//
#include <hip/hip_runtime.h>
#include <math.h>

#define LSEQ 2048
#define NB 8
#define NCH 64
#define NTOT (NB*NCH*LSEQ)   // 1048576
#define NROWS (NB*NCH)       // 512
#define PT 16                // ode eval tile (positions per block)

__device__ __forceinline__ float geluf(float x){
    return 0.5f*x*(1.0f+erff(x*0.70710678118654752f));
}
__device__ __forceinline__ float siluf(float x){
    return x/(1.0f+expf(-x));
}
__device__ __forceinline__ float sigf(float x){
    return 1.0f/(1.0f+expf(-x));
}

// ---------------- weight transpose: w[64][64][3] -> wt[192][64] --------------
__global__ __launch_bounds__(256) void wtrans_kernel(const float* __restrict__ w,
                                                     float* __restrict__ wt){
    int idx = blockIdx.x*256 + threadIdx.x;   // 12288 total
    int j = idx >> 6, co = idx & 63;
    wt[idx] = w[co*192 + j];
}

// ---------------- stat = mean over L ----------------------------------------
__global__ __launch_bounds__(256) void stat_kernel(const float* __restrict__ in,
                                                   float* __restrict__ stat){
    int r = blockIdx.x, tid = threadIdx.x;
    const float* p = in + (size_t)r*LSEQ;
    float acc = 0.f;
    for (int i=tid;i<LSEQ;i+=256) acc += p[i];
    for (int o=32;o>0;o>>=1) acc += __shfl_down(acc,o,64);
    __shared__ float red[4];
    if ((tid&63)==0) red[tid>>6]=acc;
    __syncthreads();
    if (tid==0) stat[r] = (red[0]+red[1]+red[2]+red[3])*(1.0f/LSEQ);
}

// ---------------- dywan MLP + filters + ortho -------------------------------
__global__ __launch_bounds__(256) void dywan_kernel(
    const float* __restrict__ stat,
    const float* __restrict__ w1, const float* __restrict__ b1,
    const float* __restrict__ wg1, const float* __restrict__ bg1,
    const float* __restrict__ wg2, const float* __restrict__ bg2,
    float* __restrict__ lo_out, float* __restrict__ hi_out,
    float* __restrict__ ortho_out)
{
    __shared__ float st[512];
    __shared__ float h1s[512];
    __shared__ float h2s[1024];
    __shared__ float fs[112];
    int tid = threadIdx.x;
    for (int i=tid;i<512;i+=256) st[i]=stat[i];
    __syncthreads();
    for (int idx=tid; idx<512; idx+=256){
        int b=idx>>6, j=idx&63;
        float acc=b1[j];
        const float* W=w1+j*64;
        for (int i=0;i<64;i++) acc += st[b*64+i]*W[i];
        h1s[idx]=geluf(acc);
    }
    __syncthreads();
    for (int idx=tid; idx<1024; idx+=256){
        int b=idx>>7, j=idx&127;
        float acc=bg1[j];
        const float* W=wg1+j*64;
        for (int i=0;i<64;i++) acc += h1s[b*64+i]*W[i];
        h2s[idx]=geluf(acc);
    }
    __syncthreads();
    if (tid<112){
        int b=tid/14, j=tid-b*14;
        float acc=bg2[j];
        const float* W=wg2+j*128;
        for (int i=0;i<128;i++) acc += h2s[b*128+i]*W[i];
        fs[tid]=acc;
    }
    __syncthreads();
    if (tid<56){
        int b=tid/7, k=tid-b*7;
        lo_out[tid]=fs[b*14+k];
        hi_out[tid]=fs[b*14+7+k];
    }
    if (tid==0){
        float smooth=0.f, shiftsum=0.f, ampsum=0.f;
        for (int b=0;b<8;b++){
            const float* l = fs + b*14;   // lo row
            float prev=0.f, nrm=0.f;
            for (int k=0;k<7;k++){ smooth += fabsf(l[k]-prev); prev=l[k]; nrm += l[k]*l[k]; }
            smooth += fabsf(prev);
            float denom = sqrtf(nrm) + 1e-8f;
            float sabs=0.f, s2=0.f;
            for (int k=0;k<7;k++){ float v=l[k]/denom; sabs+=fabsf(v); s2+=v*v; }
            shiftsum += sabs*sabs;
            ampsum += fabsf(s2-1.0f);
        }
        smooth *= (1.0f/64.0f);
        float shift = 3.0f*shiftsum/(8.0f*49.0f);
        float amp = ampsum*(1.0f/8.0f);
        *ortho_out = 0.01f*(shift+amp) + 0.1f*smooth;
    }
}

// ---------------- per-batch 7-tap filter conv (edge pad) --------------------
__global__ __launch_bounds__(256) void filt_kernel(
    const float* __restrict__ ap, const float* __restrict__ lo,
    const float* __restrict__ hi, float* __restrict__ na,
    float* __restrict__ det)
{
    int r = blockIdx.y, l0 = blockIdx.x*256, tid = threadIdx.x;
    int b = r>>6;
    __shared__ float s[262];
    __shared__ float fl[7], fh[7];
    for (int idx=tid; idx<262; idx+=256){
        int l = l0+idx-3;
        l = min(max(l,0),LSEQ-1);
        s[idx]=ap[(size_t)r*LSEQ+l];
    }
    if (tid<7) fl[tid]=lo[b*7+tid];
    else if (tid<14) fh[tid-7]=hi[b*7+tid-7];
    __syncthreads();
    float a=0.f, d=0.f;
    #pragma unroll
    for (int k=0;k<7;k++){ float v=s[tid+k]; a+=v*fl[k]; d+=v*fh[k]; }
    na[(size_t)r*LSEQ+l0+tid]=a;
    det[(size_t)r*LSEQ+l0+tid]=d;
}

// ---------------- time grid pass1: per-row stats ----------------------------
__global__ __launch_bounds__(256) void tg_pass1(const float* __restrict__ C,
                                                float* __restrict__ rowstats){
    __shared__ float sh[2048];
    __shared__ float red[28];
    int r = blockIdx.x, tid = threadIdx.x;
    const float* s = C + (size_t)r*LSEQ;
    for (int i=tid;i<2048;i+=256) sh[i]=s[i];
    __syncthreads();
    float ssq=0.f;
    for (int i=tid;i<2048;i+=256){ float v=sh[i]; ssq+=v*v; }
    float mn=1e30f, mx=-1e30f, s0=0.f,s1=0.f,s2=0.f,s3=0.f;
    for (int j=tid;j<2047;j+=256){
        int k0 = (j-2>0)? j-2:0;
        int k1 = (j+2<2046)? j+2:2046;
        float acc=0.f;
        for (int k=k0;k<=k1;k++) acc += fabsf(sh[k+1]-sh[k]);
        float inten = acc*0.2f;
        mn=fminf(mn,inten); mx=fmaxf(mx,inten);
        if (j<511)  s0+=inten;
        if (j<1023) s1+=inten;
        if (j<1534) s2+=inten;
        if (j<2046) s3+=inten;
    }
    float vals[7]={mn,mx,s0,s1,s2,s3,ssq};
    for (int o=32;o>0;o>>=1){
        vals[0]=fminf(vals[0],__shfl_down(vals[0],o,64));
        vals[1]=fmaxf(vals[1],__shfl_down(vals[1],o,64));
        vals[2]+=__shfl_down(vals[2],o,64);
        vals[3]+=__shfl_down(vals[3],o,64);
        vals[4]+=__shfl_down(vals[4],o,64);
        vals[5]+=__shfl_down(vals[5],o,64);
        vals[6]+=__shfl_down(vals[6],o,64);
    }
    int lane=tid&63, w=tid>>6;
    if (lane==0) for (int q=0;q<7;q++) red[w*7+q]=vals[q];
    __syncthreads();
    if (tid==0){
        rowstats[r*8+0]=fminf(fminf(red[0],red[7]),fminf(red[14],red[21]));
        rowstats[r*8+1]=fmaxf(fmaxf(red[1],red[8]),fmaxf(red[15],red[22]));
        rowstats[r*8+2]=red[2]+red[9]+red[16]+red[23];
        rowstats[r*8+3]=red[3]+red[10]+red[17]+red[24];
        rowstats[r*8+4]=red[4]+red[11]+red[18]+red[25];
        rowstats[r*8+5]=red[5]+red[12]+red[19]+red[26];
        rowstats[r*8+6]=red[6]+red[13]+red[20]+red[27];
    }
}

// ---------------- time grid finalize + modulation vectors -------------------
__global__ __launch_bounds__(256) void tg_finalize(
    const float* __restrict__ rs,
    const float* __restrict__ wt, const float* __restrict__ bt,
    const float* __restrict__ wm, const float* __restrict__ bm,
    const float* __restrict__ emb, int lvl,
    float* __restrict__ ts_out, float* __restrict__ modsc,
    float* __restrict__ modbi, float* __restrict__ ein,
    float* __restrict__ eout)
{
    int tid=threadIdx.x;
    __shared__ float red[28];
    __shared__ float stv[9];
    __shared__ float temb[144];
    float mn=1e30f,mx=-1e30f,a0=0.f,a1=0.f,a2=0.f,a3=0.f,m3=-1e30f;
    for (int r=tid;r<512;r+=256){
        mn=fminf(mn,rs[r*8+0]); mx=fmaxf(mx,rs[r*8+1]);
        a0+=rs[r*8+2]; a1+=rs[r*8+3]; a2+=rs[r*8+4]; a3+=rs[r*8+5];
        m3=fmaxf(m3,rs[r*8+5]);
    }
    float vals[7]={mn,mx,a0,a1,a2,a3,m3};
    for (int o=32;o>0;o>>=1){
        vals[0]=fminf(vals[0],__shfl_down(vals[0],o,64));
        vals[1]=fmaxf(vals[1],__shfl_down(vals[1],o,64));
        vals[2]+=__shfl_down(vals[2],o,64);
        vals[3]+=__shfl_down(vals[3],o,64);
        vals[4]+=__shfl_down(vals[4],o,64);
        vals[5]+=__shfl_down(vals[5],o,64);
        vals[6]=fmaxf(vals[6],__shfl_down(vals[6],o,64));
    }
    int lane=tid&63, w=tid>>6;
    if (lane==0) for (int q=0;q<7;q++) red[w*7+q]=vals[q];
    // per-batch energy of input + zero e_out
    if (tid<8){
        float e=0.f;
        for (int c=0;c<64;c++) e += rs[(tid*64+c)*8+6];
        ein[tid]=e*(1.0f/131072.0f);
        eout[tid]=0.f;
    }
    __syncthreads();
    if (tid==0){
        float mnv=fminf(fminf(red[0],red[7]),fminf(red[14],red[21]));
        float mxv=fmaxf(fmaxf(red[1],red[8]),fmaxf(red[15],red[22]));
        float s0=red[2]+red[9]+red[16]+red[23];
        float s1=red[3]+red[10]+red[17]+red[24];
        float s2=red[4]+red[11]+red[18]+red[25];
        float s3=red[5]+red[12]+red[19]+red[26];
        float m3v=fmaxf(fmaxf(red[6],red[13]),fmaxf(red[20],red[27]));
        const float idxs[5]={0.f,511.f,1023.f,1534.f,2046.f};
        float tsv[5];
        if (mxv-mnv < 1e-8f){
            for (int k=0;k<5;k++) tsv[k]=idxs[k]/2046.0f;
        } else {
            float a = 0.9f/(mxv-mnv+1e-30f);
            float bb = 0.1f - a*mnv;
            float gmax = a*m3v + bb*2046.0f;
            float sums[5]={0.f,s0,s1,s2,s3};
            tsv[0]=0.f;
            for (int k=1;k<5;k++)
                tsv[k]=(a*(sums[k]*(1.0f/512.0f)) + bb*idxs[k])/gmax;
        }
        for (int k=0;k<5;k++){ ts_out[k]=tsv[k]; stv[2*k]=tsv[k]; }
        for (int k=0;k<4;k++) stv[2*k+1]=tsv[k] + 0.5f*(tsv[k+1]-tsv[k]);
    }
    __syncthreads();
    if (tid<144){
        int m=tid>>4, i=tid&15;
        float z = wt[lvl*16+i]*stv[m] + bt[lvl*16+i];
        temb[tid]=siluf(z);
    }
    __syncthreads();
    for (int idx=tid; idx<1152; idx+=256){
        int m=idx>>7, c=idx&127;
        float g=bm[lvl*128+c];
        const float* W=wm+(size_t)(lvl*128+c)*16;
        const float* te=temb+m*16;
        for (int i=0;i<16;i++) g += W[i]*te[i];
        if (c<64) modsc[m*64+c]=1.0f+g+emb[(lvl*8+lvl)*64+c];
        else      modbi[m*64+(c-64)]=g;
    }
}

// ---------------- fused ode_f eval (conv-gelu-conv-mod-silu) ----------------
// Tile: PT=16 positions, grid (128,8)=1024 blocks, 256 threads (4 waves).
// Wave w covers co in [w*16, w*16+16): co = w*16 + (lane>>2); ps = lane&3.
// Weight footprint per wave per conv = 12 KB (one 64B line per (ci,tap)).
__global__ __launch_bounds__(256) void ode_eval_kernel(
    const float* __restrict__ yin, const float* __restrict__ kprev,
    const float* __restrict__ w1t, const float* __restrict__ b1,
    const float* __restrict__ w2t, const float* __restrict__ b2,
    const float* __restrict__ modsc, const float* __restrict__ modbi,
    const float* __restrict__ ts, int step, int eval,
    float* __restrict__ kout, float* __restrict__ acc,
    float* __restrict__ yout, float* __restrict__ eout, int do_energy)
{
    __shared__ float ye[64][21];   // u in [0,20): l = l0-2+u  (pad to 21)
    __shared__ float hs[64][19];   // v in [0,18): h pos = l0-1+v (pad to 19)
    __shared__ float red[4];
    const int tid=threadIdx.x;
    const int b=blockIdx.y;
    const int l0=blockIdx.x*PT;
    const float dt = ts[step+1]-ts[step];
    const float alpha=(eval==0)?0.f:((eval==3)?dt:0.5f*dt);
    const int tslot=2*step+((eval==0)?0:((eval==3)?2:1));
    // stage0: y_eval = yin + alpha*kprev, halo 2, zero-pad outside [0,LSEQ)
    for (int idx=tid; idx<64*20; idx+=256){
        int ci=idx/20, u=idx-ci*20;
        int l=l0+u-2;
        float v=0.f;
        if (l>=0 && l<LSEQ){
            size_t gi=(size_t)(b*64+ci)*LSEQ+l;
            v=yin[gi];
            if (eval!=0) v+=alpha*kprev[gi];
        }
        ye[ci][u]=v;
    }
    __syncthreads();
    const int w=tid>>6, lane=tid&63;
    const int co = w*16 + (lane>>2);
    const int ps = lane&3;
    // conv1 + gelu -> hs ; h positions v in [0,18), thread handles [v0,v0+n)
    {
        const int v0 = (ps<2)? ps*5 : 10+(ps-2)*4;
        const int n  = (ps<2)? 5:4;
        float a[5];
        const float bb=b1[co];
        #pragma unroll
        for (int i=0;i<5;i++) a[i]=bb;
        for (int ci=0;ci<64;ci++){
            const float* wp = w1t + ci*192 + co;
            float w0=wp[0], w1_=wp[64], w2_=wp[128];
            float x[7];
            #pragma unroll
            for (int j=0;j<7;j++) x[j]=ye[ci][v0+j];
            #pragma unroll
            for (int i=0;i<5;i++) a[i]+=w0*x[i]+w1_*x[i+1]+w2_*x[i+2];
        }
        for (int i=0;i<n;i++){
            int ph = l0 + v0 + i - 1;   // global h position
            hs[co][v0+i] = (ph>=0 && ph<LSEQ)? geluf(a[i]) : 0.f;
        }
    }
    __syncthreads();
    // conv2 + modulation + silu - leak -> kv ; out positions [p0,p0+4)
    float kv[4];
    {
        const int p0 = ps*4;
        float c[4];
        const float bb=b2[co];
        #pragma unroll
        for (int i=0;i<4;i++) c[i]=bb;
        for (int ci=0;ci<64;ci++){
            const float* wp = w2t + ci*192 + co;
            float w0=wp[0], w1_=wp[64], w2_=wp[128];
            float x[6];
            #pragma unroll
            for (int j=0;j<6;j++) x[j]=hs[ci][p0+j];
            #pragma unroll
            for (int i=0;i<4;i++) c[i]+=w0*x[i]+w1_*x[i+1]+w2_*x[i+2];
        }
        const float sc=modsc[tslot*64+co];
        const float bi=modbi[tslot*64+co];
        #pragma unroll
        for (int i=0;i<4;i++){
            float m=c[i]*sc+bi;
            kv[i]=siluf(m)-0.1f*ye[co][p0+i+2];
        }
    }
    __syncthreads();
    {
        const int p0 = ps*4;
        #pragma unroll
        for (int i=0;i<4;i++) hs[co][p0+i]=kv[i];
    }
    __syncthreads();
    // epilogue: coalesced-ish global updates (16 consecutive floats per row seg)
    float esum=0.f;
    const float dt6=dt/6.0f;
    for (int idx=tid; idx<1024; idx+=256){
        int ci=idx>>4, p=idx&15;
        float k=hs[ci][p];
        size_t gi=(size_t)(b*64+ci)*LSEQ + l0+p;
        if (eval==0){ kout[gi]=k; acc[gi]=k; }
        else if (eval<3){ kout[gi]=k; acc[gi]+=2.0f*k; }
        else {
            float yn=yin[gi]+dt6*(acc[gi]+k);
            yout[gi]=yn;
            esum+=yn*yn;
        }
    }
    if (do_energy){
        for (int o=32;o>0;o>>=1) esum+=__shfl_down(esum,o,64);
        if ((tid&63)==0) red[tid>>6]=esum;
        __syncthreads();
        if (tid==0) atomicAdd(&eout[b], red[0]+red[1]+red[2]+red[3]);
    }
}

// ---------------- energy renorm ---------------------------------------------
__global__ __launch_bounds__(256) void scale_kernel(
    const float* __restrict__ y, const float* __restrict__ ein,
    const float* __restrict__ eout, float* __restrict__ o)
{
    int idx = blockIdx.x*256 + threadIdx.x;
    int b = idx>>17;   // 64*2048 = 131072 per batch
    float eo = eout[b]*(1.0f/131072.0f);
    o[idx] = y[idx]*sqrtf(ein[b]/(eo+1e-8f));
}

// ---------------- 1x1 attention, detail *= (1+a) in place -------------------
__global__ __launch_bounds__(256) void attn_kernel(
    const float* __restrict__ cur, float* __restrict__ detail,
    const float* __restrict__ a1w, const float* __restrict__ a1b,
    const float* __restrict__ a2w, const float* __restrict__ a2b)
{
    __shared__ float c[64][64];
    __shared__ float hid[16][64];
    const int tid=threadIdx.x, b=blockIdx.y, l0=blockIdx.x*64;
    for (int idx=tid; idx<4096; idx+=256){
        int ci=idx>>6, p=idx&63;
        c[ci][p]=cur[(size_t)(b*64+ci)*LSEQ+l0+p];
    }
    __syncthreads();
    for (int idx=tid; idx<1024; idx+=256){
        int h=idx>>6, p=idx&63;
        float acc=a1b[h];
        const float* W=a1w+h*64;
        for (int ci=0;ci<64;ci++) acc += W[ci]*c[ci][p];
        hid[h][p]=geluf(acc);
    }
    __syncthreads();
    for (int idx=tid; idx<4096; idx+=256){
        int co=idx>>6, p=idx&63;
        float acc=a2b[co];
        const float* W=a2w+co*16;
        #pragma unroll
        for (int h=0;h<16;h++) acc += W[h]*hid[h][p];
        float a=sigf(acc);
        size_t gi=(size_t)(b*64+co)*LSEQ+l0+p;
        detail[gi] *= (1.0f+a);
    }
}

// ---------------- gate conv + residual update -------------------------------
__global__ __launch_bounds__(256) void gate_kernel(
    const float* __restrict__ cur, const float* __restrict__ detail,
    const float* __restrict__ gwt, const float* __restrict__ gb,
    float* __restrict__ curout)
{
    __shared__ float yc[64][66];
    __shared__ float dtile[64][65];
    const int tid=threadIdx.x, b=blockIdx.y, l0=blockIdx.x*64;
    for (int idx=tid; idx<64*66; idx+=256){
        int ci=idx/66, u=idx-ci*66;
        int l=l0+u-1;
        yc[ci][u]=(l>=0 && l<LSEQ)? cur[(size_t)(b*64+ci)*LSEQ+l] : 0.f;
    }
    for (int idx=tid; idx<4096; idx+=256){
        int ci=idx>>6, p=idx&63;
        dtile[ci][p]=detail[(size_t)(b*64+ci)*LSEQ+l0+p];
    }
    __syncthreads();
    const int co=tid&63, g=tid>>6;
    const int p0=g*16;
    float a[16];
    float bb=gb[co];
    #pragma unroll
    for (int i=0;i<16;i++) a[i]=bb;
    for (int ci=0;ci<64;ci++){
        float w0=gwt[(ci*3+0)*64+co];
        float w1_=gwt[(ci*3+1)*64+co];
        float w2_=gwt[(ci*3+2)*64+co];
        float x[18];
        #pragma unroll
        for (int j=0;j<18;j++) x[j]=yc[ci][p0+j];
        #pragma unroll
        for (int i=0;i<16;i++) a[i] += w0*x[i]+w1_*x[i+1]+w2_*x[i+2];
    }
    float r[16];
    #pragma unroll
    for (int i=0;i<16;i++){
        float gt=sigf(a[i]);
        r[i]=yc[co][p0+i+1]+gt*dtile[co][p0+i];
    }
    __syncthreads();
    #pragma unroll
    for (int i=0;i<16;i++) dtile[co][p0+i]=r[i];
    __syncthreads();
    for (int idx=tid; idx<4096; idx+=256){
        int ci=idx>>6, p=idx&63;
        curout[(size_t)(b*64+ci)*LSEQ+l0+p]=dtile[ci][p];
    }
}

extern "C" void kernel_launch(void* const* d_in, const int* in_sizes, int n_in,
                              void* d_out, int out_size, void* d_ws, size_t ws_size,
                              hipStream_t stream)
{
    (void)in_sizes; (void)n_in; (void)out_size; (void)ws_size;
    const float* x       =(const float*)d_in[0];
    const float* dy_w1   =(const float*)d_in[1];
    const float* dy_b1   =(const float*)d_in[2];
    const float* dy_wg1  =(const float*)d_in[3];
    const float* dy_bg1  =(const float*)d_in[4];
    const float* dy_wg2  =(const float*)d_in[5];
    const float* dy_bg2  =(const float*)d_in[6];
    const float* ode_c1w =(const float*)d_in[7];
    const float* ode_c1b =(const float*)d_in[8];
    const float* ode_c2w =(const float*)d_in[9];
    const float* ode_c2b =(const float*)d_in[10];
    const float* ode_wt  =(const float*)d_in[11];
    const float* ode_bt  =(const float*)d_in[12];
    const float* ode_wm  =(const float*)d_in[13];
    const float* ode_bm  =(const float*)d_in[14];
    const float* ode_emb =(const float*)d_in[15];
    const float* gate_w  =(const float*)d_in[16];
    const float* gate_b  =(const float*)d_in[17];
    const float* attn1_w =(const float*)d_in[18];
    const float* attn1_b =(const float*)d_in[19];
    const float* attn2_w =(const float*)d_in[20];
    const float* attn2_b =(const float*)d_in[21];
    float* out=(float*)d_out;
    float* ws=(float*)d_ws;
    const size_t N=NTOT;
    // workspace layout (floats): needs ~36.6 MB
    float* A0 =ws;
    float* Y0 =ws+N;       // also decomposition ping buffer
    float* D1 =ws+2*N;
    float* D2 =ws+3*N;
    float* D3 =ws+4*N;
    float* Y1 =ws+5*N;
    float* K0 =ws+6*N;
    float* K1 =ws+7*N;
    float* ACC=ws+8*N;
    float* SM =ws+9*N;
    float* stat_ws =SM;
    float* lo_ws   =SM+512;
    float* hi_ws   =SM+576;
    float* rowstats=SM+1024;   // 512*8
    float* ts_ws   =SM+5200;   // 5
    float* modsc   =SM+5248;   // 9*64
    float* modbi   =SM+5824;   // 9*64
    float* ein     =SM+6400;   // 8
    float* eoutb   =SM+6408;   // 8
    float* WT      =SM+8192;   // 8 * 12288 (ode conv weights, transposed)
    float* WTG     =WT+8*12288;// 3 * 12288 (gate weights, transposed)

    dim3 blk(256);

    // one-time weight transposes (per call; cheap)
    for (int lvl=0;lvl<4;lvl++){
        wtrans_kernel<<<48,blk,0,stream>>>(ode_c1w+(size_t)lvl*12288, WT+(size_t)(2*lvl)*12288);
        wtrans_kernel<<<48,blk,0,stream>>>(ode_c2w+(size_t)lvl*12288, WT+(size_t)(2*lvl+1)*12288);
    }
    for (int i=0;i<3;i++)
        wtrans_kernel<<<48,blk,0,stream>>>(gate_w+(size_t)i*12288, WTG+(size_t)i*12288);

    // ---- wavelet decomposition (3 levels) ----
    const float* cura=x;
    float* outsA[3]={A0, Y0, A0};
    float* outsD[3]={D1, D2, D3};
    for (int lv=0; lv<3; lv++){
        stat_kernel<<<NROWS,blk,0,stream>>>(cura, stat_ws);
        dywan_kernel<<<1,blk,0,stream>>>(stat_ws, dy_w1,dy_b1,dy_wg1,dy_bg1,dy_wg2,dy_bg2,
                                         lo_ws, hi_ws, out+4*N);
        filt_kernel<<<dim3(8,NROWS),blk,0,stream>>>(cura, lo_ws, hi_ws, outsA[lv], outsD[lv]);
        cura=outsA[lv];
    }
    const float* coeff[4]={A0,D1,D2,D3};

    // ---- per-level adaptive grid + RK4 + energy renorm ----
    for (int lvl=0;lvl<4;lvl++){
        tg_pass1<<<NROWS,blk,0,stream>>>(coeff[lvl], rowstats);
        tg_finalize<<<1,blk,0,stream>>>(rowstats, ode_wt, ode_bt, ode_wm, ode_bm,
                                        ode_emb, lvl, ts_ws, modsc, modbi, ein, eoutb);
        const float* w1t=WT+(size_t)(2*lvl)*12288;
        const float* w2t=WT+(size_t)(2*lvl+1)*12288;
        const float* b1=ode_c1b+lvl*64;
        const float* b2=ode_c2b+lvl*64;
        float* youts[4]={Y0,Y1,Y0,Y1};
        for (int step=0;step<4;step++){
            const float* yin=(step==0)?coeff[lvl]:youts[step-1];
            for (int ev=0;ev<4;ev++){
                const float* kp=(ev==0)?nullptr:((ev==1)?K0:((ev==2)?K1:K0));
                float* ko=(ev==0)?K0:((ev==1)?K1:((ev==2)?K0:nullptr));
                float* yo=(ev==3)?youts[step]:nullptr;
                int doe=(step==3 && ev==3)?1:0;
                ode_eval_kernel<<<dim3(LSEQ/PT,NB),blk,0,stream>>>(
                    yin,kp,w1t,b1,w2t,b2,modsc,modbi,ts_ws,step,ev,ko,ACC,yo,eoutb,doe);
            }
        }
        scale_kernel<<<NTOT/256,blk,0,stream>>>(Y1, ein, eoutb, out+(size_t)lvl*N);
    }

    // ---- reconstruction ----
    // i=2: detail = evolved[3] (out slot 3, unchanged); current: out0 -> Y0
    gate_kernel<<<dim3(32,NB),blk,0,stream>>>(out+0*N, out+3*N, WTG+2*12288, gate_b+2*64, Y0);
    // i=1: attn modifies out slot 2 in place, then gate: Y0 -> Y1
    attn_kernel<<<dim3(32,NB),blk,0,stream>>>(Y0, out+2*N, attn1_w+1024, attn1_b+16,
                                              attn2_w+1024, attn2_b+64);
    gate_kernel<<<dim3(32,NB),blk,0,stream>>>(Y0, out+2*N, WTG+1*12288, gate_b+64, Y1);
    // i=0: attn modifies out slot 1 in place, then gate: Y1 -> out slot 0
    attn_kernel<<<dim3(32,NB),blk,0,stream>>>(Y1, out+1*N, attn1_w, attn1_b,
                                              attn2_w, attn2_b);
    gate_kernel<<<dim3(32,NB),blk,0,stream>>>(Y1, out+1*N, WTG, gate_b, out+0*N);
}

// Round 4
// 1862.387 us; speedup vs baseline: 1.4110x; 1.3453x over previous
//
#include <hip/hip_runtime.h>
#include <math.h>

#define LSEQ 2048
#define NB 8
#define NCH 64
#define NTOT (NB*NCH*LSEQ)   // 1048576
#define NROWS (NB*NCH)       // 512
#define TP 32                // ode eval tile (positions per block)

__device__ __forceinline__ float geluf(float x){
    return 0.5f*x*(1.0f+erff(x*0.70710678118654752f));
}
__device__ __forceinline__ float siluf(float x){
    return x/(1.0f+expf(-x));
}
__device__ __forceinline__ float sigf(float x){
    return 1.0f/(1.0f+expf(-x));
}

// ---------------- weight transpose: w[64][64][3] -> wt[192][64] --------------
__global__ __launch_bounds__(256) void wtrans_kernel(const float* __restrict__ w,
                                                     float* __restrict__ wt){
    int idx = blockIdx.x*256 + threadIdx.x;   // 12288 total
    int j = idx >> 6, co = idx & 63;
    wt[idx] = w[co*192 + j];
}

// ---------------- stat = mean over L ----------------------------------------
__global__ __launch_bounds__(256) void stat_kernel(const float* __restrict__ in,
                                                   float* __restrict__ stat){
    int r = blockIdx.x, tid = threadIdx.x;
    const float* p = in + (size_t)r*LSEQ;
    float acc = 0.f;
    for (int i=tid;i<LSEQ;i+=256) acc += p[i];
    for (int o=32;o>0;o>>=1) acc += __shfl_down(acc,o,64);
    __shared__ float red[4];
    if ((tid&63)==0) red[tid>>6]=acc;
    __syncthreads();
    if (tid==0) stat[r] = (red[0]+red[1]+red[2]+red[3])*(1.0f/LSEQ);
}

// ---------------- dywan MLP + filters + ortho -------------------------------
__global__ __launch_bounds__(256) void dywan_kernel(
    const float* __restrict__ stat,
    const float* __restrict__ w1, const float* __restrict__ b1,
    const float* __restrict__ wg1, const float* __restrict__ bg1,
    const float* __restrict__ wg2, const float* __restrict__ bg2,
    float* __restrict__ lo_out, float* __restrict__ hi_out,
    float* __restrict__ ortho_out)
{
    __shared__ float st[512];
    __shared__ float h1s[512];
    __shared__ float h2s[1024];
    __shared__ float fs[112];
    int tid = threadIdx.x;
    for (int i=tid;i<512;i+=256) st[i]=stat[i];
    __syncthreads();
    for (int idx=tid; idx<512; idx+=256){
        int b=idx>>6, j=idx&63;
        float acc=b1[j];
        const float* W=w1+j*64;
        for (int i=0;i<64;i++) acc += st[b*64+i]*W[i];
        h1s[idx]=geluf(acc);
    }
    __syncthreads();
    for (int idx=tid; idx<1024; idx+=256){
        int b=idx>>7, j=idx&127;
        float acc=bg1[j];
        const float* W=wg1+j*64;
        for (int i=0;i<64;i++) acc += h1s[b*64+i]*W[i];
        h2s[idx]=geluf(acc);
    }
    __syncthreads();
    if (tid<112){
        int b=tid/14, j=tid-b*14;
        float acc=bg2[j];
        const float* W=wg2+j*128;
        for (int i=0;i<128;i++) acc += h2s[b*128+i]*W[i];
        fs[tid]=acc;
    }
    __syncthreads();
    if (tid<56){
        int b=tid/7, k=tid-b*7;
        lo_out[tid]=fs[b*14+k];
        hi_out[tid]=fs[b*14+7+k];
    }
    if (tid==0){
        float smooth=0.f, shiftsum=0.f, ampsum=0.f;
        for (int b=0;b<8;b++){
            const float* l = fs + b*14;   // lo row
            float prev=0.f, nrm=0.f;
            for (int k=0;k<7;k++){ smooth += fabsf(l[k]-prev); prev=l[k]; nrm += l[k]*l[k]; }
            smooth += fabsf(prev);
            float denom = sqrtf(nrm) + 1e-8f;
            float sabs=0.f, s2=0.f;
            for (int k=0;k<7;k++){ float v=l[k]/denom; sabs+=fabsf(v); s2+=v*v; }
            shiftsum += sabs*sabs;
            ampsum += fabsf(s2-1.0f);
        }
        smooth *= (1.0f/64.0f);
        float shift = 3.0f*shiftsum/(8.0f*49.0f);
        float amp = ampsum*(1.0f/8.0f);
        *ortho_out = 0.01f*(shift+amp) + 0.1f*smooth;
    }
}

// ---------------- per-batch 7-tap filter conv (edge pad) --------------------
__global__ __launch_bounds__(256) void filt_kernel(
    const float* __restrict__ ap, const float* __restrict__ lo,
    const float* __restrict__ hi, float* __restrict__ na,
    float* __restrict__ det)
{
    int r = blockIdx.y, l0 = blockIdx.x*256, tid = threadIdx.x;
    int b = r>>6;
    __shared__ float s[262];
    __shared__ float fl[7], fh[7];
    for (int idx=tid; idx<262; idx+=256){
        int l = l0+idx-3;
        l = min(max(l,0),LSEQ-1);
        s[idx]=ap[(size_t)r*LSEQ+l];
    }
    if (tid<7) fl[tid]=lo[b*7+tid];
    else if (tid<14) fh[tid-7]=hi[b*7+tid-7];
    __syncthreads();
    float a=0.f, d=0.f;
    #pragma unroll
    for (int k=0;k<7;k++){ float v=s[tid+k]; a+=v*fl[k]; d+=v*fh[k]; }
    na[(size_t)r*LSEQ+l0+tid]=a;
    det[(size_t)r*LSEQ+l0+tid]=d;
}

// ---------------- time grid pass1: per-row stats (batched over levels) ------
__global__ __launch_bounds__(256) void tg_pass1(const float* __restrict__ CB,
                                                float* __restrict__ rowstats){
    __shared__ float sh[2048];
    __shared__ float red[28];
    int r = blockIdx.x, lvl = blockIdx.y, tid = threadIdx.x;
    const float* s = CB + (size_t)lvl*NTOT + (size_t)r*LSEQ;
    float* rso = rowstats + (size_t)(lvl*NROWS+r)*8;
    for (int i=tid;i<2048;i+=256) sh[i]=s[i];
    __syncthreads();
    float ssq=0.f;
    for (int i=tid;i<2048;i+=256){ float v=sh[i]; ssq+=v*v; }
    float mn=1e30f, mx=-1e30f, s0=0.f,s1=0.f,s2=0.f,s3=0.f;
    for (int j=tid;j<2047;j+=256){
        int k0 = (j-2>0)? j-2:0;
        int k1 = (j+2<2046)? j+2:2046;
        float acc=0.f;
        for (int k=k0;k<=k1;k++) acc += fabsf(sh[k+1]-sh[k]);
        float inten = acc*0.2f;
        mn=fminf(mn,inten); mx=fmaxf(mx,inten);
        if (j<511)  s0+=inten;
        if (j<1023) s1+=inten;
        if (j<1534) s2+=inten;
        if (j<2046) s3+=inten;
    }
    float vals[7]={mn,mx,s0,s1,s2,s3,ssq};
    for (int o=32;o>0;o>>=1){
        vals[0]=fminf(vals[0],__shfl_down(vals[0],o,64));
        vals[1]=fmaxf(vals[1],__shfl_down(vals[1],o,64));
        vals[2]+=__shfl_down(vals[2],o,64);
        vals[3]+=__shfl_down(vals[3],o,64);
        vals[4]+=__shfl_down(vals[4],o,64);
        vals[5]+=__shfl_down(vals[5],o,64);
        vals[6]+=__shfl_down(vals[6],o,64);
    }
    int lane=tid&63, w=tid>>6;
    if (lane==0) for (int q=0;q<7;q++) red[w*7+q]=vals[q];
    __syncthreads();
    if (tid==0){
        rso[0]=fminf(fminf(red[0],red[7]),fminf(red[14],red[21]));
        rso[1]=fmaxf(fmaxf(red[1],red[8]),fmaxf(red[15],red[22]));
        rso[2]=red[2]+red[9]+red[16]+red[23];
        rso[3]=red[3]+red[10]+red[17]+red[24];
        rso[4]=red[4]+red[11]+red[18]+red[25];
        rso[5]=red[5]+red[12]+red[19]+red[26];
        rso[6]=red[6]+red[13]+red[20]+red[27];
    }
}

// ---------------- time grid finalize + modulation (grid = 4 levels) ---------
__global__ __launch_bounds__(256) void tg_finalize(
    const float* __restrict__ rowstats,
    const float* __restrict__ wt, const float* __restrict__ bt,
    const float* __restrict__ wm, const float* __restrict__ bm,
    const float* __restrict__ emb,
    float* __restrict__ ts_out, float* __restrict__ modsc,
    float* __restrict__ modbi, float* __restrict__ ein,
    float* __restrict__ eout)
{
    int tid=threadIdx.x;
    const int lvl=blockIdx.x;
    const float* rs = rowstats + (size_t)lvl*NROWS*8;
    __shared__ float red[28];
    __shared__ float stv[9];
    __shared__ float temb[144];
    float mn=1e30f,mx=-1e30f,a0=0.f,a1=0.f,a2=0.f,a3=0.f,m3=-1e30f;
    for (int r=tid;r<512;r+=256){
        mn=fminf(mn,rs[r*8+0]); mx=fmaxf(mx,rs[r*8+1]);
        a0+=rs[r*8+2]; a1+=rs[r*8+3]; a2+=rs[r*8+4]; a3+=rs[r*8+5];
        m3=fmaxf(m3,rs[r*8+5]);
    }
    float vals[7]={mn,mx,a0,a1,a2,a3,m3};
    for (int o=32;o>0;o>>=1){
        vals[0]=fminf(vals[0],__shfl_down(vals[0],o,64));
        vals[1]=fmaxf(vals[1],__shfl_down(vals[1],o,64));
        vals[2]+=__shfl_down(vals[2],o,64);
        vals[3]+=__shfl_down(vals[3],o,64);
        vals[4]+=__shfl_down(vals[4],o,64);
        vals[5]+=__shfl_down(vals[5],o,64);
        vals[6]=fmaxf(vals[6],__shfl_down(vals[6],o,64));
    }
    int lane=tid&63, w=tid>>6;
    if (lane==0) for (int q=0;q<7;q++) red[w*7+q]=vals[q];
    if (tid<8){
        float e=0.f;
        for (int c=0;c<64;c++) e += rs[(tid*64+c)*8+6];
        ein[lvl*8+tid]=e*(1.0f/131072.0f);
        eout[lvl*8+tid]=0.f;
    }
    __syncthreads();
    if (tid==0){
        float mnv=fminf(fminf(red[0],red[7]),fminf(red[14],red[21]));
        float mxv=fmaxf(fmaxf(red[1],red[8]),fmaxf(red[15],red[22]));
        float s0=red[2]+red[9]+red[16]+red[23];
        float s1=red[3]+red[10]+red[17]+red[24];
        float s2=red[4]+red[11]+red[18]+red[25];
        float s3=red[5]+red[12]+red[19]+red[26];
        float m3v=fmaxf(fmaxf(red[6],red[13]),fmaxf(red[20],red[27]));
        const float idxs[5]={0.f,511.f,1023.f,1534.f,2046.f};
        float tsv[5];
        if (mxv-mnv < 1e-8f){
            for (int k=0;k<5;k++) tsv[k]=idxs[k]/2046.0f;
        } else {
            float a = 0.9f/(mxv-mnv+1e-30f);
            float bb = 0.1f - a*mnv;
            float gmax = a*m3v + bb*2046.0f;
            float sums[5]={0.f,s0,s1,s2,s3};
            tsv[0]=0.f;
            for (int k=1;k<5;k++)
                tsv[k]=(a*(sums[k]*(1.0f/512.0f)) + bb*idxs[k])/gmax;
        }
        for (int k=0;k<5;k++){ ts_out[lvl*8+k]=tsv[k]; stv[2*k]=tsv[k]; }
        for (int k=0;k<4;k++) stv[2*k+1]=tsv[k] + 0.5f*(tsv[k+1]-tsv[k]);
    }
    __syncthreads();
    if (tid<144){
        int m=tid>>4, i=tid&15;
        float z = wt[lvl*16+i]*stv[m] + bt[lvl*16+i];
        temb[tid]=siluf(z);
    }
    __syncthreads();
    for (int idx=tid; idx<1152; idx+=256){
        int m=idx>>7, c=idx&127;
        float g=bm[lvl*128+c];
        const float* W=wm+(size_t)(lvl*128+c)*16;
        const float* te=temb+m*16;
        for (int i=0;i<16;i++) g += W[i]*te[i];
        if (c<64) modsc[lvl*576+m*64+c]=1.0f+g+emb[(lvl*8+lvl)*64+c];
        else      modbi[lvl*576+m*64+(c-64)]=g;
    }
}

// ---------------- fused ode_f eval, batched over 4 levels -------------------
// grid (64, 8, 4): blockIdx = (pos tile, batch, level). block = 256 (4 waves).
// lane = output channel co (coalesced weight loads, broadcast LDS reads).
// Wave w computes h positions [w's slice of 34] then out positions [w*8,w*8+8).
__global__ __launch_bounds__(256,8) void ode_eval_all(
    const float* __restrict__ yinB, const float* __restrict__ kprevB,
    float* __restrict__ koutB, float* __restrict__ accB,
    float* __restrict__ youtB,
    const float* __restrict__ wtB, const float* __restrict__ c1bB,
    const float* __restrict__ c2bB,
    const float* __restrict__ modscB, const float* __restrict__ modbiB,
    const float* __restrict__ tsB, float* __restrict__ eoutB,
    int step, int eval, int do_energy)
{
    __shared__ float ye[64][TP+5];   // u in [0,TP+4): l = l0-2+u
    __shared__ float hs[64][TP+3];   // v in [0,TP+2): h pos = l0-1+v
    __shared__ float red[4];
    const int tid=threadIdx.x;
    const int lvl=blockIdx.z;
    const int b=blockIdx.y;
    const int l0=blockIdx.x*TP;
    const size_t loff=(size_t)lvl*NTOT;
    const float* yin = yinB + loff;
    const float* kprev = kprevB + loff;
    float* kout = koutB + loff;
    float* acc = accB + loff;
    float* yout = youtB + loff;
    const float* w1t = wtB + (size_t)lvl*24576;
    const float* w2t = w1t + 12288;
    const float dt = tsB[lvl*8+step+1]-tsB[lvl*8+step];
    const float alpha=(eval==0)?0.f:((eval==3)?dt:0.5f*dt);
    const int tslot=2*step+((eval==0)?0:((eval==3)?2:1));
    // stage0: y_eval = yin + alpha*kprev, halo 2, zero-pad outside [0,LSEQ)
    for (int idx=tid; idx<64*(TP+4); idx+=256){
        int ci=idx/(TP+4), u=idx-ci*(TP+4);
        int l=l0+u-2;
        float v=0.f;
        if (l>=0 && l<LSEQ){
            size_t gi=(size_t)(b*64+ci)*LSEQ+l;
            v=yin[gi];
            if (eval!=0) v+=alpha*kprev[gi];
        }
        ye[ci][u]=v;
    }
    __syncthreads();
    const int w=tid>>6, co=tid&63;
    // stage1: conv1+gelu -> hs[co][v], v in [0,34). waves 0,1: 9; waves 2,3: 8.
    {
        const int v0 = (w<2)? w*9 : 18+(w-2)*8;
        const int n  = (w<2)? 9:8;
        float a[9];
        const float bb=c1bB[lvl*64+co];
        #pragma unroll
        for (int i=0;i<9;i++) a[i]=bb;
        #pragma unroll 8
        for (int ci=0;ci<64;ci++){
            const float* wp = w1t + ci*192 + co;
            float w0=wp[0], w1_=wp[64], w2_=wp[128];
            float x[11];
            #pragma unroll
            for (int j=0;j<11;j++) x[j]=ye[ci][v0+j];
            #pragma unroll
            for (int i=0;i<9;i++) a[i]+=w0*x[i]+w1_*x[i+1]+w2_*x[i+2];
        }
        for (int i=0;i<n;i++){
            int ph = l0 - 1 + v0 + i;
            hs[co][v0+i] = (ph>=0 && ph<LSEQ)? geluf(a[i]) : 0.f;
        }
    }
    __syncthreads();
    // stage2: conv2 + modulation + silu - leak -> kv (8 positions per thread)
    float kv[8];
    {
        const int p0 = w*8;
        float c[8];
        const float bb=c2bB[lvl*64+co];
        #pragma unroll
        for (int i=0;i<8;i++) c[i]=bb;
        #pragma unroll 8
        for (int ci=0;ci<64;ci++){
            const float* wp = w2t + ci*192 + co;
            float w0=wp[0], w1_=wp[64], w2_=wp[128];
            float x[10];
            #pragma unroll
            for (int j=0;j<10;j++) x[j]=hs[ci][p0+j];
            #pragma unroll
            for (int i=0;i<8;i++) c[i]+=w0*x[i]+w1_*x[i+1]+w2_*x[i+2];
        }
        const float sc=modscB[lvl*576+tslot*64+co];
        const float bi=modbiB[lvl*576+tslot*64+co];
        #pragma unroll
        for (int i=0;i<8;i++){
            float m=c[i]*sc+bi;
            kv[i]=siluf(m)-0.1f*ye[co][p0+i+2];
        }
    }
    __syncthreads();
    {
        const int p0 = w*8;
        #pragma unroll
        for (int i=0;i<8;i++) hs[co][p0+i]=kv[i];
    }
    __syncthreads();
    // epilogue: coalesced global updates
    float esum=0.f;
    const float dt6=dt/6.0f;
    for (int idx=tid; idx<64*TP; idx+=256){
        int ci=idx>>5, p=idx&(TP-1);
        float k=hs[ci][p];
        size_t gi=(size_t)(b*64+ci)*LSEQ + l0+p;
        if (eval==0){ kout[gi]=k; acc[gi]=k; }
        else if (eval<3){ kout[gi]=k; acc[gi]+=2.0f*k; }
        else {
            float yn=yin[gi]+dt6*(acc[gi]+k);
            yout[gi]=yn;
            esum+=yn*yn;
        }
    }
    if (do_energy){
        for (int o=32;o>0;o>>=1) esum+=__shfl_down(esum,o,64);
        if ((tid&63)==0) red[tid>>6]=esum;
        __syncthreads();
        if (tid==0) atomicAdd(&eoutB[lvl*8+b], red[0]+red[1]+red[2]+red[3]);
    }
}

// ---------------- energy renorm (batched over levels) -----------------------
__global__ __launch_bounds__(256) void scale_kernel(
    const float* __restrict__ y, const float* __restrict__ ein,
    const float* __restrict__ eout, float* __restrict__ o)
{
    int idx = blockIdx.x*256 + threadIdx.x;
    int lb = idx>>17;   // (lvl*8+b), 131072 elems each
    float eo = eout[lb]*(1.0f/131072.0f);
    o[idx] = y[idx]*sqrtf(ein[lb]/(eo+1e-8f));
}

// ---------------- 1x1 attention, detail *= (1+a) in place -------------------
__global__ __launch_bounds__(256) void attn_kernel(
    const float* __restrict__ cur, float* __restrict__ detail,
    const float* __restrict__ a1w, const float* __restrict__ a1b,
    const float* __restrict__ a2w, const float* __restrict__ a2b)
{
    __shared__ float c[64][64];
    __shared__ float hid[16][64];
    const int tid=threadIdx.x, b=blockIdx.y, l0=blockIdx.x*64;
    for (int idx=tid; idx<4096; idx+=256){
        int ci=idx>>6, p=idx&63;
        c[ci][p]=cur[(size_t)(b*64+ci)*LSEQ+l0+p];
    }
    __syncthreads();
    for (int idx=tid; idx<1024; idx+=256){
        int h=idx>>6, p=idx&63;
        float acc=a1b[h];
        const float* W=a1w+h*64;
        for (int ci=0;ci<64;ci++) acc += W[ci]*c[ci][p];
        hid[h][p]=geluf(acc);
    }
    __syncthreads();
    for (int idx=tid; idx<4096; idx+=256){
        int co=idx>>6, p=idx&63;
        float acc=a2b[co];
        const float* W=a2w+co*16;
        #pragma unroll
        for (int h=0;h<16;h++) acc += W[h]*hid[h][p];
        float a=sigf(acc);
        size_t gi=(size_t)(b*64+co)*LSEQ+l0+p;
        detail[gi] *= (1.0f+a);
    }
}

// ---------------- gate conv + residual update -------------------------------
__global__ __launch_bounds__(256) void gate_kernel(
    const float* __restrict__ cur, const float* __restrict__ detail,
    const float* __restrict__ gwt, const float* __restrict__ gb,
    float* __restrict__ curout)
{
    __shared__ float yc[64][66];
    __shared__ float dtile[64][65];
    const int tid=threadIdx.x, b=blockIdx.y, l0=blockIdx.x*64;
    for (int idx=tid; idx<64*66; idx+=256){
        int ci=idx/66, u=idx-ci*66;
        int l=l0+u-1;
        yc[ci][u]=(l>=0 && l<LSEQ)? cur[(size_t)(b*64+ci)*LSEQ+l] : 0.f;
    }
    for (int idx=tid; idx<4096; idx+=256){
        int ci=idx>>6, p=idx&63;
        dtile[ci][p]=detail[(size_t)(b*64+ci)*LSEQ+l0+p];
    }
    __syncthreads();
    const int co=tid&63, g=tid>>6;
    const int p0=g*16;
    float a[16];
    float bb=gb[co];
    #pragma unroll
    for (int i=0;i<16;i++) a[i]=bb;
    for (int ci=0;ci<64;ci++){
        float w0=gwt[(ci*3+0)*64+co];
        float w1_=gwt[(ci*3+1)*64+co];
        float w2_=gwt[(ci*3+2)*64+co];
        float x[18];
        #pragma unroll
        for (int j=0;j<18;j++) x[j]=yc[ci][p0+j];
        #pragma unroll
        for (int i=0;i<16;i++) a[i] += w0*x[i]+w1_*x[i+1]+w2_*x[i+2];
    }
    float r[16];
    #pragma unroll
    for (int i=0;i<16;i++){
        float gt=sigf(a[i]);
        r[i]=yc[co][p0+i+1]+gt*dtile[co][p0+i];
    }
    __syncthreads();
    #pragma unroll
    for (int i=0;i<16;i++) dtile[co][p0+i]=r[i];
    __syncthreads();
    for (int idx=tid; idx<4096; idx+=256){
        int ci=idx>>6, p=idx&63;
        curout[(size_t)(b*64+ci)*LSEQ+l0+p]=dtile[ci][p];
    }
}

extern "C" void kernel_launch(void* const* d_in, const int* in_sizes, int n_in,
                              void* d_out, int out_size, void* d_ws, size_t ws_size,
                              hipStream_t stream)
{
    (void)in_sizes; (void)n_in; (void)out_size; (void)ws_size;
    const float* x       =(const float*)d_in[0];
    const float* dy_w1   =(const float*)d_in[1];
    const float* dy_b1   =(const float*)d_in[2];
    const float* dy_wg1  =(const float*)d_in[3];
    const float* dy_bg1  =(const float*)d_in[4];
    const float* dy_wg2  =(const float*)d_in[5];
    const float* dy_bg2  =(const float*)d_in[6];
    const float* ode_c1w =(const float*)d_in[7];
    const float* ode_c1b =(const float*)d_in[8];
    const float* ode_c2w =(const float*)d_in[9];
    const float* ode_c2b =(const float*)d_in[10];
    const float* ode_wt  =(const float*)d_in[11];
    const float* ode_bt  =(const float*)d_in[12];
    const float* ode_wm  =(const float*)d_in[13];
    const float* ode_bm  =(const float*)d_in[14];
    const float* ode_emb =(const float*)d_in[15];
    const float* gate_w  =(const float*)d_in[16];
    const float* gate_b  =(const float*)d_in[17];
    const float* attn1_w =(const float*)d_in[18];
    const float* attn1_b =(const float*)d_in[19];
    const float* attn2_w =(const float*)d_in[20];
    const float* attn2_b =(const float*)d_in[21];
    float* out=(float*)d_out;
    float* ws=(float*)d_ws;
    const size_t N=NTOT;
    // workspace layout (floats): 20N + ~190K ≈ 85 MB (ws is ~256 MB)
    float* CB = ws;          // coeff[4]: A0, D1, D2, D3 (4N)
    float* PB = ws+4*N;      // y ping (4 levels) — also decomp temps T0,T1
    float* QB = ws+8*N;      // y pong (4 levels)
    float* K0B= ws+12*N;
    float* K1B= ws+16*N;
    float* SM = ws+20*N;
    float* stat_ws =SM;          // 512
    float* lo_ws   =SM+512;      // 64
    float* hi_ws   =SM+576;      // 64
    float* rowstats=SM+1024;     // 4*512*8 = 16384
    float* ts_ws   =SM+17408;    // 4*8
    float* modsc   =SM+17536;    // 4*576
    float* modbi   =SM+19840;    // 4*576
    float* ein     =SM+22144;    // 32
    float* eoutb   =SM+22176;    // 32
    float* WT      =SM+24576;    // 8*12288 (ode conv weights, transposed)
    float* WTG     =WT+8*12288;  // 3*12288 (gate weights, transposed)
    float* ACCB    =out;         // d_out[0..4N) free until scale_kernel

    dim3 blk(256);

    for (int lvl=0;lvl<4;lvl++){
        wtrans_kernel<<<48,blk,0,stream>>>(ode_c1w+(size_t)lvl*12288, WT+(size_t)(2*lvl)*12288);
        wtrans_kernel<<<48,blk,0,stream>>>(ode_c2w+(size_t)lvl*12288, WT+(size_t)(2*lvl+1)*12288);
    }
    for (int i=0;i<3;i++)
        wtrans_kernel<<<48,blk,0,stream>>>(gate_w+(size_t)i*12288, WTG+(size_t)i*12288);

    // ---- wavelet decomposition (3 levels, sequential) ----
    const float* cura=x;
    float* outsA[3]={PB, PB+N, CB};      // T0, T1, A0-final
    float* outsD[3]={CB+N, CB+2*N, CB+3*N};
    for (int lv=0; lv<3; lv++){
        stat_kernel<<<NROWS,blk,0,stream>>>(cura, stat_ws);
        dywan_kernel<<<1,blk,0,stream>>>(stat_ws, dy_w1,dy_b1,dy_wg1,dy_bg1,dy_wg2,dy_bg2,
                                         lo_ws, hi_ws, out+4*N);
        filt_kernel<<<dim3(8,NROWS),blk,0,stream>>>(cura, lo_ws, hi_ws, outsA[lv], outsD[lv]);
        cura=outsA[lv];
    }

    // ---- adaptive grids + modulation for all 4 levels ----
    tg_pass1<<<dim3(NROWS,4),blk,0,stream>>>(CB, rowstats);
    tg_finalize<<<4,blk,0,stream>>>(rowstats, ode_wt, ode_bt, ode_wm, ode_bm,
                                    ode_emb, ts_ws, modsc, modbi, ein, eoutb);

    // ---- RK4: 16 evals, each batched over 4 levels ----
    const float* yins[4]={CB, PB, QB, PB};
    float*       youts[4]={PB, QB, PB, QB};
    for (int step=0;step<4;step++){
        for (int ev=0;ev<4;ev++){
            const float* kp=(ev==0)?K0B:((ev==1)?K0B:((ev==2)?K1B:K0B));
            float* ko=(ev==0)?K0B:((ev==1)?K1B:((ev==2)?K0B:K0B));
            int doe=(step==3 && ev==3)?1:0;
            ode_eval_all<<<dim3(LSEQ/TP,NB,4),blk,0,stream>>>(
                yins[step],kp,ko,ACCB,youts[step],
                WT,ode_c1b,ode_c2b,modsc,modbi,ts_ws,eoutb,step,ev,doe);
        }
    }
    scale_kernel<<<4*NTOT/256,blk,0,stream>>>(QB, ein, eoutb, out);

    // ---- reconstruction ----
    // i=2: current: out0 -> PB; detail = out slot 3 (unchanged)
    gate_kernel<<<dim3(32,NB),blk,0,stream>>>(out+0*N, out+3*N, WTG+2*12288, gate_b+2*64, PB);
    // i=1: attn modifies out slot 2 in place, then gate: PB -> QB
    attn_kernel<<<dim3(32,NB),blk,0,stream>>>(PB, out+2*N, attn1_w+1024, attn1_b+16,
                                              attn2_w+1024, attn2_b+64);
    gate_kernel<<<dim3(32,NB),blk,0,stream>>>(PB, out+2*N, WTG+1*12288, gate_b+64, QB);
    // i=0: attn modifies out slot 1 in place, then gate: QB -> out slot 0
    attn_kernel<<<dim3(32,NB),blk,0,stream>>>(QB, out+1*N, attn1_w, attn1_b,
                                              attn2_w, attn2_b);
    gate_kernel<<<dim3(32,NB),blk,0,stream>>>(QB, out+1*N, WTG, gate_b, out+0*N);
}